// Round 4
// baseline (135.662 us; speedup 1.0000x reference)
//
#include <hip/hip_runtime.h>

// ClebschCombiningSingleUnrolled: out[mu] += mult * X1[m1] * X2[m2] (elementwise over N*D)
// M=9 channels, K=100 terms, P = N*D = 1048576 floats per channel.
//
// R4: high-TLP single-buffer design. 1-wave blocks, TILE=256 floats, TPB=2,
// LDS=18KB -> 8 blocks/CU (2 waves/SIMD, no barriers). Segments padded to
// multiples of 4 (zero-mult entries) so the k-loop is chunked: 4 plan entries
// -> 8 independent ds_read_b128 per chunk for ILP. One vmcnt(0) per tile.

#define M_CH 9
#define TILE 256            // floats per channel per tile (64 lanes x float4)
#define THREADS 64          // one wave per block
#define TPB 2               // tiles per block -> grid = P/512 = 2048 = 8 blocks/CU
#define PLAN_PAD 128        // padded plan capacity (max 100 + 9*3 = 127)
#define ROWB (TILE * 4)     // bytes per channel row in LDS (1024)

typedef const void __attribute__((address_space(1))) * gcptr;
typedef void       __attribute__((address_space(3))) * lsptr;

__global__ __launch_bounds__(128) void prep_kernel(
    const int* __restrict__ m1, const int* __restrict__ m2,
    const int* __restrict__ mu, const float* __restrict__ mult,
    int K, int* __restrict__ ws) {
    __shared__ int smu[PLAN_PAD];
    __shared__ int s_len[16], s_pstart[16];
    const int t = threadIdx.x;
    if (t < K) smu[t] = mu[t];
    __syncthreads();
    // per-channel counts
    if (t < M_CH) {
        int c = 0;
        for (int k = 0; k < K; ++k) c += (smu[k] == t) ? 1 : 0;
        s_len[t] = c;
    }
    __syncthreads();
    // padded prefix sum (pad each segment to multiple of 4)
    if (t == 0) {
        int acc = 0;
        for (int m = 0; m < M_CH; ++m) {
            s_pstart[m] = acc;
            acc += (s_len[m] + 3) & ~3;
        }
        s_pstart[M_CH] = acc;
    }
    __syncthreads();
    if (t <= M_CH) ws[t] = s_pstart[t];        // padded segment bounds
    int4* plan = (int4*)(ws + 16);
    if (t < PLAN_PAD) {                        // zero-mult pad entries first
        int4 e; e.x = 0; e.y = M_CH * ROWB; e.z = 0; e.w = 0;
        plan[t] = e;
    }
    __syncthreads();                           // drain pad writes before scatter
    if (t < K) {
        int r = 0;                             // rank within my segment
        for (int k = 0; k < t; ++k) r += (smu[k] == smu[t]) ? 1 : 0;
        int4 e;
        e.x = m1[t] * ROWB;                    // X1 channel row byte offset
        e.y = (M_CH + m2[t]) * ROWB;           // X2 channel row byte offset
        e.z = __float_as_int(mult[t]);
        e.w = 0;
        plan[s_pstart[smu[t]] + r] = e;
    }
}

__global__ __launch_bounds__(THREADS) void cleb_kernel(
    const float* __restrict__ X1, const float* __restrict__ X2,
    const int* __restrict__ ws, float* __restrict__ out, int P) {
    __shared__ float lds[2 * M_CH * TILE];     // 18 KB -> 8 blocks/CU
    const int tid = threadIdx.x;
    const int base0 = blockIdx.x * (TILE * TPB);

    int seg[M_CH + 1];
    #pragma unroll
    for (int i = 0; i <= M_CH; ++i) seg[i] = ws[i];
    const int4* plan = (const int4*)(ws + 16);
    const char* ldsb = (const char*)lds;
    const int lane_off = tid * 16;

    #pragma unroll
    for (int t = 0; t < TPB; ++t) {
        const int base = base0 + t * TILE;
        const float* s1 = X1 + base + tid * 4;
        const float* s2 = X2 + base + tid * 4;
        // all LDS reads of the previous tile are complete (acc deps), but make
        // it explicit before overwriting the single buffer
        asm volatile("s_waitcnt lgkmcnt(0)" ::: "memory");
        __builtin_amdgcn_sched_barrier(0);
        #pragma unroll
        for (int m = 0; m < M_CH; ++m) {
            __builtin_amdgcn_global_load_lds((gcptr)(s1 + m * P),
                                             (lsptr)(lds + m * TILE + tid * 4), 16, 0, 0);
            __builtin_amdgcn_global_load_lds((gcptr)(s2 + m * P),
                                             (lsptr)(lds + (M_CH + m) * TILE + tid * 4), 16, 0, 0);
        }
        asm volatile("s_waitcnt vmcnt(0)" ::: "memory");   // tile staged
        __builtin_amdgcn_sched_barrier(0);

        float* outp = out + base + tid * 4;
        #pragma unroll
        for (int m = 0; m < M_CH; ++m) {
            float4 acc = make_float4(0.f, 0.f, 0.f, 0.f);
            const int s_ = seg[m], e_ = seg[m + 1];
            #pragma unroll 2
            for (int k = s_; k < e_; k += 4) {             // padded: no remainder
                const int4 e0 = plan[k + 0];
                const int4 e1 = plan[k + 1];
                const int4 e2 = plan[k + 2];
                const int4 e3 = plan[k + 3];
                const float4 a0 = *(const float4*)(ldsb + e0.x + lane_off);
                const float4 b0 = *(const float4*)(ldsb + e0.y + lane_off);
                const float4 a1 = *(const float4*)(ldsb + e1.x + lane_off);
                const float4 b1 = *(const float4*)(ldsb + e1.y + lane_off);
                const float4 a2 = *(const float4*)(ldsb + e2.x + lane_off);
                const float4 b2 = *(const float4*)(ldsb + e2.y + lane_off);
                const float4 a3 = *(const float4*)(ldsb + e3.x + lane_off);
                const float4 b3 = *(const float4*)(ldsb + e3.y + lane_off);
                const float c0 = __int_as_float(e0.z);
                const float c1 = __int_as_float(e1.z);
                const float c2 = __int_as_float(e2.z);
                const float c3 = __int_as_float(e3.z);
                acc.x = fmaf(c0 * a0.x, b0.x, acc.x);
                acc.y = fmaf(c0 * a0.y, b0.y, acc.y);
                acc.z = fmaf(c0 * a0.z, b0.z, acc.z);
                acc.w = fmaf(c0 * a0.w, b0.w, acc.w);
                acc.x = fmaf(c1 * a1.x, b1.x, acc.x);
                acc.y = fmaf(c1 * a1.y, b1.y, acc.y);
                acc.z = fmaf(c1 * a1.z, b1.z, acc.z);
                acc.w = fmaf(c1 * a1.w, b1.w, acc.w);
                acc.x = fmaf(c2 * a2.x, b2.x, acc.x);
                acc.y = fmaf(c2 * a2.y, b2.y, acc.y);
                acc.z = fmaf(c2 * a2.z, b2.z, acc.z);
                acc.w = fmaf(c2 * a2.w, b2.w, acc.w);
                acc.x = fmaf(c3 * a3.x, b3.x, acc.x);
                acc.y = fmaf(c3 * a3.y, b3.y, acc.y);
                acc.z = fmaf(c3 * a3.z, b3.z, acc.z);
                acc.w = fmaf(c3 * a3.w, b3.w, acc.w);
            }
            *(float4*)(outp + m * P) = acc;                // coalesced 16B store
        }
    }
}

extern "C" void kernel_launch(void* const* d_in, const int* in_sizes, int n_in,
                              void* d_out, int out_size, void* d_ws, size_t ws_size,
                              hipStream_t stream) {
    const float* X1   = (const float*)d_in[0];
    const float* X2   = (const float*)d_in[1];
    const int*   m1   = (const int*)d_in[2];
    const int*   m2   = (const int*)d_in[3];
    const int*   mu   = (const int*)d_in[4];
    const float* mult = (const float*)d_in[5];
    float* out = (float*)d_out;
    int*   ws  = (int*)d_ws;

    const int K = in_sizes[2];                 // 100
    const int P = in_sizes[0] / M_CH;          // 1048576

    prep_kernel<<<1, 128, 0, stream>>>(m1, m2, mu, mult, K, ws);
    cleb_kernel<<<P / (TILE * TPB), THREADS, 0, stream>>>(X1, X2, ws, out, P);
}